// Round 16
// baseline (311.224 us; speedup 1.0000x reference)
//
#include <hip/hip_runtime.h>
#include <hip/hip_bf16.h>
#include <math.h>

#define RR 16

typedef __attribute__((ext_vector_type(8))) short bf16x8;
typedef __attribute__((ext_vector_type(4))) float f32x4;

#define MFMA16(a, b, c) __builtin_amdgcn_mfma_f32_16x16x32_bf16((a), (b), (c), 0, 0, 0)

static __device__ __forceinline__ unsigned short f2bf(float f) {   // staging only
    union { float f; unsigned u; } v; v.f = f;
    unsigned r = v.u + 0x7fffu + ((v.u >> 16) & 1u);
    return (unsigned short)(r >> 16);
}
static __device__ __forceinline__ float bf2f(unsigned short h) {
    union { float f; unsigned u; } v; v.u = ((unsigned)h) << 16; return v.f;
}

// packed f32->bf16 hi/lo split (compiler-selected v_cvt_pk_bf16_f32, no asm)
static __device__ __forceinline__ void pk4(float a, float b, float c, float d,
                                           uint2* hi, uint2* lo) {
    union { __hip_bfloat162 b; unsigned u; } H01, H23, L01, L23;
    H01.b = __float22bfloat162_rn(float2{a, b});   // lo16 = bf16(a), hi16 = bf16(b)
    H23.b = __float22bfloat162_rn(float2{c, d});
    const float r0 = __uint_as_float(H01.u << 16);
    const float r1 = __uint_as_float(H01.u & 0xffff0000u);
    const float r2 = __uint_as_float(H23.u << 16);
    const float r3 = __uint_as_float(H23.u & 0xffff0000u);
    L01.b = __float22bfloat162_rn(float2{a - r0, b - r1});
    L23.b = __float22bfloat162_rn(float2{c - r2, d - r3});
    hi->x = H01.u; hi->y = H23.u;
    lo->x = L01.u; lo->y = L23.u;
}
// hi-only packed conversion: 4 floats -> 2 dwords of bf16
static __device__ __forceinline__ uint2 pk4hi(float a, float b, float c, float d) {
    union { __hip_bfloat162 b; unsigned u; } H01, H23;
    H01.b = __float22bfloat162_rn(float2{a, b});
    H23.b = __float22bfloat162_rn(float2{c, d});
    return uint2{H01.u, H23.u};
}

__global__ __launch_bounds__(512, 2)
void siren_mfma(const float* __restrict__ pos, const float* __restrict__ grid,
                const float* __restrict__ W1, const float* __restrict__ b1,
                const float* __restrict__ W2, const float* __restrict__ b2,
                const float* __restrict__ W3, const float* __restrict__ b3,
                float* __restrict__ out, int N)
{
    // ---- LDS: 119,808 B ----
    __shared__ short sW2T[128 * 128];    // A of G1: (i=it*16+m, j=ks*32+8g+e), hi only
    __shared__ short sW2N[128 * 128];    // A of G2: (j=jt*16+m, i=ks*32+8g+e), hi only
    __shared__ short sW1T_h[128 * 32];   // A of G0: (j,k) 30*W1 / 30*b1, hi
    __shared__ short sW1T_l[128 * 32];   // lo residual
    __shared__ short sW1B_h[16 * 128];   // A of G3: (k=m, j), 30*W1, else 0 (hi only)
    __shared__ float sb2[128];
    __shared__ float sW3[128];
    __shared__ short sHTS_h[8][16 * 128]; // per-wave [point m][feat] h -> t -> s (hi)
    const int tid = threadIdx.x;

    // ================= weight staging (once per block, 512 threads) =================
    {   // W2T: thread (i = tid&127, ks = tid>>7) covers j = ks*32 .. +31
        const int i = tid & 127, ks = tid >> 7;
        const int base = ((i >> 4) * 2048) + ks * 512 + (i & 15) * 8;
        #pragma unroll
        for (int g = 0; g < 4; ++g) {
            bf16x8 h8;
            #pragma unroll
            for (int e = 0; e < 8; ++e)
                h8[e] = (short)f2bf(W2[(ks * 32 + g * 8 + e) * 128 + i]);
            *(bf16x8*)&sW2T[base + g * 128] = h8;
        }
    }
    {   // W2N: thread (j = tid&127, ks = tid>>7) covers i = ks*32 .. +31 (contiguous)
        const int j = tid & 127, ks = tid >> 7;
        const int base = ((j >> 4) * 2048) + ks * 512 + (j & 15) * 8;
        const float4* __restrict__ w4 = (const float4*)&W2[j * 128 + ks * 32];
        #pragma unroll
        for (int g = 0; g < 4; ++g) {
            const float4 a = w4[g * 2];
            const float4 b = w4[g * 2 + 1];
            bf16x8 h8;
            h8[0] = (short)f2bf(a.x); h8[1] = (short)f2bf(a.y);
            h8[2] = (short)f2bf(a.z); h8[3] = (short)f2bf(a.w);
            h8[4] = (short)f2bf(b.x); h8[5] = (short)f2bf(b.y);
            h8[6] = (short)f2bf(b.z); h8[7] = (short)f2bf(b.w);
            *(bf16x8*)&sW2N[base + g * 128] = h8;
        }
    }
    if (tid < 128) {   // W1T hi/lo, PRE-SCALED by 30 (c0 = 30*z1 directly)
        const int j = tid;
        const int base = ((j >> 4) * 512) + (j & 15) * 8;
        bf16x8 h8, l8;
        #pragma unroll
        for (int e = 0; e < 8; ++e) {
            const float v = (e < 5) ? 30.f * W1[e * 128 + j]
                                    : (e == 5 ? 30.f * b1[j] : 0.f);
            const unsigned short hs = f2bf(v);
            h8[e] = (short)hs;
            l8[e] = (short)f2bf(v - bf2f(hs));
        }
        *(bf16x8*)&sW1T_h[base] = h8;
        *(bf16x8*)&sW1T_l[base] = l8;
        bf16x8 z8 = {0, 0, 0, 0, 0, 0, 0, 0};
        #pragma unroll
        for (int g = 1; g < 4; ++g) {
            *(bf16x8*)&sW1T_h[base + g * 128] = z8;
            *(bf16x8*)&sW1T_l[base + g * 128] = z8;
        }
        sb2[j] = b2[j];
        sW3[j] = W3[j];
    }
    if (tid < 256) {   // W1B hi only, PRE-SCALED by 30
        const int k = tid & 15, gg = (tid >> 4) & 3, ks = tid >> 6;
        const int base = ks * 512 + gg * 128 + k * 8;
        bf16x8 h8;
        #pragma unroll
        for (int e = 0; e < 8; ++e) {
            const int j = ks * 32 + gg * 8 + e;
            const float v = (k < 5) ? 30.f * W1[k * 128 + j] : 0.f;
            h8[e] = (short)f2bf(v);
        }
        *(bf16x8*)&sW1B_h[base] = h8;
    }
    const float b3v = b3[0];
    __syncthreads();

    // ================= main loop: 16 point-tiles of 16 per wave =================
    const int lane = tid & 63;
    const int wv = tid >> 6;
    const int g = lane >> 4;
    const int m = lane & 15;

    char* __restrict__ hhB = (char*)sHTS_h[wv];
    const int rbB = lane * 16;                                     // byte read base
    const int wbB = (g >> 1) * 256 + m * 16 + (g & 1) * 8;         // byte write base
    const int rbS = lane * 8;                                      // short idx (weights)
    const float2* __restrict__ g2 = (const float2*)grid;

    #pragma unroll 1
    for (int pt = 0; pt < 16; ++pt) {
        const int p = blockIdx.x * 2048 + wv * 256 + pt * 16 + m;
        const int pc = (p < N) ? p : (N - 1);

        // ---- x row (trilerp fwd): state is LOCAL to this block — the output
        //      epilogue recomputes it from a fresh pos load, so nothing below
        //      carries across the four GEMM phases (live-set cut).
        bf16x8 xbh, xbl;
        {
            const float px = pos[3 * pc + 0];
            const float py = pos[3 * pc + 1];
            const float pz = pos[3 * pc + 2];
            const float ux = (px + 1.f) * 7.5f;
            const float uy = (py + 1.f) * 7.5f;
            const float uz = (pz + 1.f) * 7.5f;
            int ix = (int)floorf(ux); ix = ix < 0 ? 0 : (ix > RR - 2 ? RR - 2 : ix);
            int iy = (int)floorf(uy); iy = iy < 0 ? 0 : (iy > RR - 2 ? RR - 2 : iy);
            int iz = (int)floorf(uz); iz = iz < 0 ? 0 : (iz > RR - 2 ? RR - 2 : iz);
            const float fx = ux - (float)ix;
            const float fy = uy - (float)iy;
            const float fz = uz - (float)iz;
            const int cbase = (ix * RR + iy) * RR + iz;
            const float wx0 = 1.f - fx, wx1 = fx;
            const float wy0 = 1.f - fy, wy1 = fy;
            const float wz0 = 1.f - fz, wz1 = fz;
            const float2 c000 = g2[cbase];
            const float2 c001 = g2[cbase + 1];
            const float2 c010 = g2[cbase + RR];
            const float2 c011 = g2[cbase + RR + 1];
            const float2 c100 = g2[cbase + RR * RR];
            const float2 c101 = g2[cbase + RR * RR + 1];
            const float2 c110 = g2[cbase + RR * RR + RR];
            const float2 c111 = g2[cbase + RR * RR + RR + 1];
            const float w000 = wx0 * wy0 * wz0, w001 = wx0 * wy0 * wz1;
            const float w010 = wx0 * wy1 * wz0, w011 = wx0 * wy1 * wz1;
            const float w100 = wx1 * wy0 * wz0, w101 = wx1 * wy0 * wz1;
            const float w110 = wx1 * wy1 * wz0, w111 = wx1 * wy1 * wz1;
            const float e0 = w000 * c000.x + w001 * c001.x + w010 * c010.x
                           + w011 * c011.x + w100 * c100.x + w101 * c101.x
                           + w110 * c110.x + w111 * c111.x;
            const float e1 = w000 * c000.y + w001 * c001.y + w010 * c010.y
                           + w011 * c011.y + w100 * c100.y + w101 * c101.y
                           + w110 * c110.y + w111 * c111.y;
            union { bf16x8 v; uint2 u[2]; } XH, XL;
            pk4(e0, e1, px, py, &XH.u[0], &XL.u[0]);
            pk4(pz, 1.f, 0.f, 0.f, &XH.u[1], &XL.u[1]);
            xbh = XH.v; xbl = XL.v;
        }

        // ---- G0: c0 = 30*z1^T[j][p] (3-term; W1T pre-scaled by 30) ----
        f32x4 c0[8];
        #pragma unroll
        for (int jt = 0; jt < 8; ++jt) {
            const bf16x8 ah = *(const bf16x8*)&sW1T_h[jt * 512 + rbS];
            const bf16x8 al = *(const bf16x8*)&sW1T_l[jt * 512 + rbS];
            f32x4 c = {0.f, 0.f, 0.f, 0.f};
            c = MFMA16(ah, xbh, c);
            c = MFMA16(ah, xbl, c);
            c = MFMA16(al, xbh, c);
            c0[jt] = c;
        }

        // ---- h-phase: sincos(c0); sin -> hts_h, cos kept in regs (cs30) ----
        f32x4 cs30[8];
        #pragma unroll
        for (int jt = 0; jt < 8; ++jt) {
            float s0, s1, s2, s3, q0, q1, q2, q3;
            __sincosf(c0[jt][0], &s0, &q0);
            __sincosf(c0[jt][1], &s1, &q1);
            __sincosf(c0[jt][2], &s2, &q2);
            __sincosf(c0[jt][3], &s3, &q3);
            cs30[jt][0] = q0; cs30[jt][1] = q1; cs30[jt][2] = q2; cs30[jt][3] = q3;
            *(uint2*)(hhB + wbB + jt * 512) = pk4hi(s0, s1, s2, s3);
        }

        // ---- G1: z2^T[i][p] = W2T(hi) x h(hi), acc seeded with b2 ----
        // ks fence (unroll 1) + it unroll 2: caps in-flight weight fragments
        f32x4 c1[8];
        #pragma unroll
        for (int it = 0; it < 8; ++it) c1[it] = *(const f32x4*)&sb2[it * 16 + 4 * g];
        __builtin_amdgcn_s_setprio(1);
        #pragma unroll 1
        for (int ks = 0; ks < 4; ++ks) {
            const bf16x8 bh = *(const bf16x8*)(hhB + ks * 1024 + rbB);
            #pragma unroll 2
            for (int it = 0; it < 8; ++it) {
                const bf16x8 a = *(const bf16x8*)&sW2T[it * 2048 + ks * 512 + rbS];
                c1[it] = MFMA16(a, bh, c1[it]);
            }
        }
        __builtin_amdgcn_s_setprio(0);

        // ---- phase 2: sdf (stored NOW, no carry) + t = W3*cos(z2) -> hts ----
        float sdfp = 0.f;
        #pragma unroll
        for (int it = 0; it < 8; ++it) {
            const f32x4 w3v = *(const f32x4*)&sW3[it * 16 + 4 * g];
            float s0, cc0, s1, cc1, s2, cc2, s3, cc3;
            __sincosf(c1[it][0], &s0, &cc0);
            __sincosf(c1[it][1], &s1, &cc1);
            __sincosf(c1[it][2], &s2, &cc2);
            __sincosf(c1[it][3], &s3, &cc3);
            sdfp = fmaf(w3v[0], s0, sdfp);
            sdfp = fmaf(w3v[1], s1, sdfp);
            sdfp = fmaf(w3v[2], s2, sdfp);
            sdfp = fmaf(w3v[3], s3, sdfp);
            *(uint2*)(hhB + wbB + it * 512) =
                pk4hi(w3v[0] * cc0, w3v[1] * cc1, w3v[2] * cc2, w3v[3] * cc3);
        }
        sdfp += __shfl_xor(sdfp, 16);
        sdfp += __shfl_xor(sdfp, 32);
        if (lane < 16 && p < N) out[p] = b3v + sdfp;

        // ---- G2: u^T[j][p] = W2N(hi) x t(hi) ----
        f32x4 c2[8];
        #pragma unroll
        for (int jt = 0; jt < 8; ++jt) c2[jt] = (f32x4){0.f, 0.f, 0.f, 0.f};
        __builtin_amdgcn_s_setprio(1);
        #pragma unroll 1
        for (int ks = 0; ks < 4; ++ks) {
            const bf16x8 bh = *(const bf16x8*)(hhB + ks * 1024 + rbB);
            #pragma unroll 2
            for (int jt = 0; jt < 8; ++jt) {
                const bf16x8 a = *(const bf16x8*)&sW2N[jt * 2048 + ks * 512 + rbS];
                c2[jt] = MFMA16(a, bh, c2[jt]);
            }
        }
        __builtin_amdgcn_s_setprio(0);

        // ---- phase 3: s_j = u_j * cos(c0) (cos from regs) -> hts (hi only) ----
        #pragma unroll
        for (int jt = 0; jt < 8; ++jt) {
            *(uint2*)(hhB + wbB + jt * 512) =
                pk4hi(c2[jt][0] * cs30[jt][0], c2[jt][1] * cs30[jt][1],
                      c2[jt][2] * cs30[jt][2], c2[jt][3] * cs30[jt][3]);
        }

        // ---- G3: dx[k][p] = (30*W1B)(hi) x s(hi), single-term ----
        f32x4 c3 = {0.f, 0.f, 0.f, 0.f};
        __builtin_amdgcn_s_setprio(1);
        #pragma unroll
        for (int ks = 0; ks < 4; ++ks) {
            const bf16x8 bh = *(const bf16x8*)(hhB + ks * 1024 + rbB);
            const bf16x8 ah = *(const bf16x8*)&sW1B_h[ks * 512 + rbS];
            c3 = MFMA16(ah, bh, c3);
        }
        __builtin_amdgcn_s_setprio(0);
        // lane m needs k=4 (dz) which lives in lane m+16, reg 0
        const float d4v = __shfl(c3[0], (lane & 15) + 16);

        // ---- outputs: trilerp state RECOMPUTED from fresh pos load ----
        if (lane < 16 && p < N) {
            const float px = pos[3 * p + 0];
            const float py = pos[3 * p + 1];
            const float pz = pos[3 * p + 2];
            const float ux = (px + 1.f) * 7.5f;
            const float uy = (py + 1.f) * 7.5f;
            const float uz = (pz + 1.f) * 7.5f;
            int ix = (int)floorf(ux); ix = ix < 0 ? 0 : (ix > RR - 2 ? RR - 2 : ix);
            int iy = (int)floorf(uy); iy = iy < 0 ? 0 : (iy > RR - 2 ? RR - 2 : iy);
            int iz = (int)floorf(uz); iz = iz < 0 ? 0 : (iz > RR - 2 ? RR - 2 : iz);
            const float fx = ux - (float)ix;
            const float fy = uy - (float)iy;
            const float fz = uz - (float)iz;
            const int cbase = (ix * RR + iy) * RR + iz;
            const float wx0 = 1.f - fx, wx1 = fx;
            const float wy0 = 1.f - fy, wy1 = fy;
            const float wz0 = 1.f - fz, wz1 = fz;
            const float de0 = c3[0], de1 = c3[1];
            const float2 r000 = g2[cbase];
            const float2 r001 = g2[cbase + 1];
            const float2 r010 = g2[cbase + RR];
            const float2 r011 = g2[cbase + RR + 1];
            const float2 r100 = g2[cbase + RR * RR];
            const float2 r101 = g2[cbase + RR * RR + 1];
            const float2 r110 = g2[cbase + RR * RR + RR];
            const float2 r111 = g2[cbase + RR * RR + RR + 1];
            const float q000 = r000.x * de0 + r000.y * de1;
            const float q001 = r001.x * de0 + r001.y * de1;
            const float q010 = r010.x * de0 + r010.y * de1;
            const float q011 = r011.x * de0 + r011.y * de1;
            const float q100 = r100.x * de0 + r100.y * de1;
            const float q101 = r101.x * de0 + r101.y * de1;
            const float q110 = r110.x * de0 + r110.y * de1;
            const float q111 = r111.x * de0 + r111.y * de1;
            const float gx = 7.5f * (wy0 * wz0 * (q100 - q000) + wy0 * wz1 * (q101 - q001)
                                   + wy1 * wz0 * (q110 - q010) + wy1 * wz1 * (q111 - q011));
            const float gy = 7.5f * (wx0 * wz0 * (q010 - q000) + wx0 * wz1 * (q011 - q001)
                                   + wx1 * wz0 * (q110 - q100) + wx1 * wz1 * (q111 - q101));
            const float gz = 7.5f * (wx0 * wy0 * (q001 - q000) + wx0 * wy1 * (q011 - q010)
                                   + wx1 * wy0 * (q101 - q100) + wx1 * wy1 * (q111 - q110));
            const bool msk = (px >= -1.f) && (px <= 1.f) && (py >= -1.f) && (py <= 1.f)
                          && (pz >= -1.f) && (pz <= 1.f);
            out[N + 3 * p + 0] = c3[2] + gx;
            out[N + 3 * p + 1] = c3[3] + gy;
            out[N + 3 * p + 2] = d4v + gz;
            out[4 * N + p] = msk ? 1.f : 0.f;
        }
    }
}

extern "C" void kernel_launch(void* const* d_in, const int* in_sizes, int n_in,
                              void* d_out, int out_size, void* d_ws, size_t ws_size,
                              hipStream_t stream) {
    const float* pos  = (const float*)d_in[0];
    const float* grid = (const float*)d_in[1];
    const float* W1   = (const float*)d_in[2];
    const float* b1   = (const float*)d_in[3];
    const float* W2   = (const float*)d_in[4];
    const float* b2   = (const float*)d_in[5];
    const float* W3   = (const float*)d_in[6];
    const float* b3   = (const float*)d_in[7];
    float* out = (float*)d_out;
    const int N = in_sizes[0] / 3;
    const int blocks = (N + 2047) / 2048;
    hipLaunchKernelGGL(siren_mfma, dim3(blocks), dim3(512), 0, stream,
                       pos, grid, W1, b1, W2, b2, W3, b3, out, N);
}

// Round 17
// 147.106 us; speedup vs baseline: 2.1157x; 2.1157x over previous
//
#include <hip/hip_runtime.h>
#include <hip/hip_bf16.h>
#include <math.h>

#define RR 16

typedef __attribute__((ext_vector_type(8))) short bf16x8;
typedef __attribute__((ext_vector_type(4))) float f32x4;
typedef __attribute__((ext_vector_type(16))) float f32x16;

#define MFMA32(a, b, c) __builtin_amdgcn_mfma_f32_32x32x16_bf16((a), (b), (c), 0, 0, 0)

static __device__ __forceinline__ unsigned short f2bf(float f) {   // staging only
    union { float f; unsigned u; } v; v.f = f;
    unsigned r = v.u + 0x7fffu + ((v.u >> 16) & 1u);
    return (unsigned short)(r >> 16);
}
static __device__ __forceinline__ float bf2f(unsigned short h) {
    union { float f; unsigned u; } v; v.u = ((unsigned)h) << 16; return v.f;
}

static __device__ __forceinline__ void pk4(float a, float b, float c, float d,
                                           uint2* hi, uint2* lo) {
    union { __hip_bfloat162 b; unsigned u; } H01, H23, L01, L23;
    H01.b = __float22bfloat162_rn(float2{a, b});
    H23.b = __float22bfloat162_rn(float2{c, d});
    const float r0 = __uint_as_float(H01.u << 16);
    const float r1 = __uint_as_float(H01.u & 0xffff0000u);
    const float r2 = __uint_as_float(H23.u << 16);
    const float r3 = __uint_as_float(H23.u & 0xffff0000u);
    L01.b = __float22bfloat162_rn(float2{a - r0, b - r1});
    L23.b = __float22bfloat162_rn(float2{c - r2, d - r3});
    hi->x = H01.u; hi->y = H23.u;
    lo->x = L01.u; lo->y = L23.u;
}
static __device__ __forceinline__ uint2 pk4hi(float a, float b, float c, float d) {
    union { __hip_bfloat162 b; unsigned u; } H01, H23;
    H01.b = __float22bfloat162_rn(float2{a, b});
    H23.b = __float22bfloat162_rn(float2{c, d});
    return uint2{H01.u, H23.u};
}

// 32x32x16 restructure: 32-point tiles. HTS element (point p, feature f) lives
// at byte (f>>4)*1024 + ((f>>3)&1)*512 + p*16 + (f&7)*2 — exactly the B-operand
// fragment order, so frag ks reads at byte ks*1024 + lane*16 (conflict-free).
// C-fragment (HW-verified): col=lane&31, row=(reg&3)+8*(reg>>2)+4*(lane>>5).
__global__ __launch_bounds__(512, 2)
void siren_mfma(const float* __restrict__ pos, const float* __restrict__ grid,
                const float* __restrict__ W1, const float* __restrict__ b1,
                const float* __restrict__ W2, const float* __restrict__ b2,
                const float* __restrict__ W3, const float* __restrict__ b3,
                float* __restrict__ out, int N)
{
    // ---- LDS: 148,480 B ----
    __shared__ short sW2T[32 * 512];   // G1 A: block(it,ks): W2[j=ks*16+hi*8+e][i=it*32+r]
    __shared__ short sW2N[32 * 512];   // G2 A: block(jt,ks): W2[j=jt*32+r][i=ks*16+hi*8+e]
    __shared__ short sW1T_h[4 * 512];  // G0 A: block(jt): 30*W1/30*b1, k=hi*8+e (hi=1 -> 0)
    __shared__ short sW1T_l[4 * 512];
    __shared__ short sW1B_h[8 * 512];  // G3 A: block(ks): rows k'=0..4 = 30*W1, else 0
    __shared__ float sb2[128];
    __shared__ float sW3[128];
    __shared__ short sHTS[8][4096];    // per-wave 8KB: h -> t -> s in B-frag layout
    const int tid = threadIdx.x;

    // ================= weight staging =================
    #pragma unroll
    for (int pass = 0; pass < 4; ++pass) {   // W2T (strided gather, L2-cached)
        const int slot = pass * 512 + tid;
        const int b = slot >> 6, l = slot & 63;
        const int i = (b >> 3) * 32 + (l & 31);
        const int j0 = (b & 7) * 16 + (l >> 5) * 8;
        bf16x8 h8;
        #pragma unroll
        for (int e = 0; e < 8; ++e) h8[e] = (short)f2bf(W2[(j0 + e) * 128 + i]);
        *(bf16x8*)&sW2T[b * 512 + l * 8] = h8;
    }
    #pragma unroll
    for (int pass = 0; pass < 4; ++pass) {   // W2N (contiguous)
        const int slot = pass * 512 + tid;
        const int b = slot >> 6, l = slot & 63;
        const int j = (b >> 3) * 32 + (l & 31);
        const int i0 = (b & 7) * 16 + (l >> 5) * 8;
        const float4 a = *(const float4*)&W2[j * 128 + i0];
        const float4 bb = *(const float4*)&W2[j * 128 + i0 + 4];
        bf16x8 h8;
        h8[0] = (short)f2bf(a.x);  h8[1] = (short)f2bf(a.y);
        h8[2] = (short)f2bf(a.z);  h8[3] = (short)f2bf(a.w);
        h8[4] = (short)f2bf(bb.x); h8[5] = (short)f2bf(bb.y);
        h8[6] = (short)f2bf(bb.z); h8[7] = (short)f2bf(bb.w);
        *(bf16x8*)&sW2N[b * 512 + l * 8] = h8;
    }
    if (tid < 256) {   // W1T hi/lo, pre-scaled by 30; k>=6 and hi=1 zero
        const int jt = tid >> 6, l = tid & 63;
        const int j = jt * 32 + (l & 31);
        const int khi = l >> 5;
        bf16x8 h8, l8;
        #pragma unroll
        for (int e = 0; e < 8; ++e) {
            const int k = khi * 8 + e;
            const float v = (k < 5) ? 30.f * W1[k * 128 + j]
                                    : (k == 5 ? 30.f * b1[j] : 0.f);
            const unsigned short hs = f2bf(v);
            h8[e] = (short)hs;
            l8[e] = (short)f2bf(v - bf2f(hs));
        }
        *(bf16x8*)&sW1T_h[jt * 512 + l * 8] = h8;
        *(bf16x8*)&sW1T_l[jt * 512 + l * 8] = l8;
    }
    {   // W1B hi only, pre-scaled by 30 (all 512 threads)
        const int ks = tid >> 6, l = tid & 63;
        const int kk = l & 31;
        const int j0 = ks * 16 + (l >> 5) * 8;
        bf16x8 h8;
        #pragma unroll
        for (int e = 0; e < 8; ++e) {
            const float v = (kk < 5) ? 30.f * W1[kk * 128 + j0 + e] : 0.f;
            h8[e] = (short)f2bf(v);
        }
        *(bf16x8*)&sW1B_h[ks * 512 + l * 8] = h8;
    }
    if (tid < 128) { sb2[tid] = b2[tid]; sW3[tid] = W3[tid]; }
    const float b3v = b3[0];
    __syncthreads();

    // ================= main loop: 8 tiles of 32 points per wave =================
    const int lane = tid & 63;
    const int wv = tid >> 6;
    const int pl = lane & 31;     // point within tile (C column)
    const int hi = lane >> 5;     // k-group / row-group half
    char* __restrict__ hhB = (char*)sHTS[wv];
    const int rbB = lane * 16;    // byte base for B-frag reads
    const int rbS = lane * 8;     // short base for weight A-frag reads
    const int wbB = pl * 16 + hi * 8;  // byte base for phase writes
    const float2* __restrict__ g2 = (const float2*)grid;

    #pragma unroll 1
    for (int pt = 0; pt < 8; ++pt) {
        const int p = blockIdx.x * 2048 + wv * 256 + pt * 32 + pl;
        const int pc = (p < N) ? p : (N - 1);

        const float px = pos[3 * pc + 0];
        const float py = pos[3 * pc + 1];
        const float pz = pos[3 * pc + 2];

        // ---- trilerp forward (2x redundant across hi) -> x fragment ----
        bf16x8 xbh, xbl;
        {
            const float ux = (px + 1.f) * 7.5f;
            const float uy = (py + 1.f) * 7.5f;
            const float uz = (pz + 1.f) * 7.5f;
            int ix = (int)floorf(ux); ix = ix < 0 ? 0 : (ix > RR - 2 ? RR - 2 : ix);
            int iy = (int)floorf(uy); iy = iy < 0 ? 0 : (iy > RR - 2 ? RR - 2 : iy);
            int iz = (int)floorf(uz); iz = iz < 0 ? 0 : (iz > RR - 2 ? RR - 2 : iz);
            const float fx = ux - (float)ix;
            const float fy = uy - (float)iy;
            const float fz = uz - (float)iz;
            const int cbase = (ix * RR + iy) * RR + iz;
            const float wx0 = 1.f - fx, wx1 = fx;
            const float wy0 = 1.f - fy, wy1 = fy;
            const float wz0 = 1.f - fz, wz1 = fz;
            const float2 c000 = g2[cbase];
            const float2 c001 = g2[cbase + 1];
            const float2 c010 = g2[cbase + RR];
            const float2 c011 = g2[cbase + RR + 1];
            const float2 c100 = g2[cbase + RR * RR];
            const float2 c101 = g2[cbase + RR * RR + 1];
            const float2 c110 = g2[cbase + RR * RR + RR];
            const float2 c111 = g2[cbase + RR * RR + RR + 1];
            const float w000 = wx0 * wy0 * wz0, w001 = wx0 * wy0 * wz1;
            const float w010 = wx0 * wy1 * wz0, w011 = wx0 * wy1 * wz1;
            const float w100 = wx1 * wy0 * wz0, w101 = wx1 * wy0 * wz1;
            const float w110 = wx1 * wy1 * wz0, w111 = wx1 * wy1 * wz1;
            const float e0 = w000 * c000.x + w001 * c001.x + w010 * c010.x
                           + w011 * c011.x + w100 * c100.x + w101 * c101.x
                           + w110 * c110.x + w111 * c111.x;
            const float e1 = w000 * c000.y + w001 * c001.y + w010 * c010.y
                           + w011 * c011.y + w100 * c100.y + w101 * c101.y
                           + w110 * c110.y + w111 * c111.y;
            union { bf16x8 v; uint2 u[2]; } XH, XL;
            pk4(e0, e1, px, py, &XH.u[0], &XL.u[0]);
            pk4(pz, 1.f, 0.f, 0.f, &XH.u[1], &XL.u[1]);
            xbh = XH.v; xbl = XL.v;
        }
        if (lane >= 32) {   // hi half supplies k=8..15 of x (all zero)
            const bf16x8 z8 = {0, 0, 0, 0, 0, 0, 0, 0};
            xbh = z8; xbl = z8;
        }

        // ---- G0 + h-phase fused per jt: c0 tile -> sin to LDS, cos packed regs ----
        uint2 csp[4][4];   // cos(30*z1) as bf16, 32 VGPRs
        #pragma unroll
        for (int jt = 0; jt < 4; ++jt) {
            const bf16x8 ah = *(const bf16x8*)&sW1T_h[jt * 512 + rbS];
            const bf16x8 al = *(const bf16x8*)&sW1T_l[jt * 512 + rbS];
            f32x16 c = {0.f,0.f,0.f,0.f,0.f,0.f,0.f,0.f,0.f,0.f,0.f,0.f,0.f,0.f,0.f,0.f};
            c = MFMA32(ah, xbh, c);
            c = MFMA32(ah, xbl, c);
            c = MFMA32(al, xbh, c);
            #pragma unroll
            for (int q = 0; q < 4; ++q) {
                float s0, s1, s2, s3, q0, q1, q2, q3;
                __sincosf(c[q * 4 + 0], &s0, &q0);
                __sincosf(c[q * 4 + 1], &s1, &q1);
                __sincosf(c[q * 4 + 2], &s2, &q2);
                __sincosf(c[q * 4 + 3], &s3, &q3);
                csp[jt][q] = pk4hi(q0, q1, q2, q3);
                *(uint2*)(hhB + jt * 2048 + (q >> 1) * 1024 + (q & 1) * 512 + wbB)
                    = pk4hi(s0, s1, s2, s3);
            }
        }

        // ---- G1: z2[128 i][32 p] = W2T x h, seeded with b2 ----
        f32x16 c1[4];
        #pragma unroll
        for (int it = 0; it < 4; ++it) {
            #pragma unroll
            for (int q = 0; q < 4; ++q) {
                const f32x4 bv = *(const f32x4*)&sb2[it * 32 + q * 8 + hi * 4];
                c1[it][q * 4 + 0] = bv[0];
                c1[it][q * 4 + 1] = bv[1];
                c1[it][q * 4 + 2] = bv[2];
                c1[it][q * 4 + 3] = bv[3];
            }
        }
        __builtin_amdgcn_s_setprio(1);
        #pragma unroll 1
        for (int ks = 0; ks < 8; ++ks) {
            const bf16x8 bh = *(const bf16x8*)(hhB + ks * 1024 + rbB);
            #pragma unroll
            for (int it = 0; it < 4; ++it) {
                const bf16x8 a = *(const bf16x8*)&sW2T[(it * 8 + ks) * 512 + rbS];
                c1[it] = MFMA32(a, bh, c1[it]);
            }
        }
        __builtin_amdgcn_s_setprio(0);

        // ---- phase 2: sdf partial + t = W3*cos(z2) -> HTS ----
        float sdfp = 0.f;
        #pragma unroll
        for (int it = 0; it < 4; ++it) {
            #pragma unroll
            for (int q = 0; q < 4; ++q) {
                const f32x4 w3v = *(const f32x4*)&sW3[it * 32 + q * 8 + hi * 4];
                float s0, cc0, s1, cc1, s2, cc2, s3, cc3;
                __sincosf(c1[it][q * 4 + 0], &s0, &cc0);
                __sincosf(c1[it][q * 4 + 1], &s1, &cc1);
                __sincosf(c1[it][q * 4 + 2], &s2, &cc2);
                __sincosf(c1[it][q * 4 + 3], &s3, &cc3);
                sdfp = fmaf(w3v[0], s0, sdfp);
                sdfp = fmaf(w3v[1], s1, sdfp);
                sdfp = fmaf(w3v[2], s2, sdfp);
                sdfp = fmaf(w3v[3], s3, sdfp);
                *(uint2*)(hhB + it * 2048 + (q >> 1) * 1024 + (q & 1) * 512 + wbB)
                    = pk4hi(w3v[0] * cc0, w3v[1] * cc1, w3v[2] * cc2, w3v[3] * cc3);
            }
        }
        sdfp += __shfl_xor(sdfp, 32);
        if (lane < 32 && p < N) out[p] = b3v + sdfp;

        // ---- G2: u[128 j][32 p] = W2N x t ----
        f32x16 c2[4];
        #pragma unroll
        for (int jt = 0; jt < 4; ++jt)
            c2[jt] = (f32x16){0.f,0.f,0.f,0.f,0.f,0.f,0.f,0.f,0.f,0.f,0.f,0.f,0.f,0.f,0.f,0.f};
        __builtin_amdgcn_s_setprio(1);
        #pragma unroll 1
        for (int ks = 0; ks < 8; ++ks) {
            const bf16x8 bh = *(const bf16x8*)(hhB + ks * 1024 + rbB);
            #pragma unroll
            for (int jt = 0; jt < 4; ++jt) {
                const bf16x8 a = *(const bf16x8*)&sW2N[(jt * 8 + ks) * 512 + rbS];
                c2[jt] = MFMA32(a, bh, c2[jt]);
            }
        }
        __builtin_amdgcn_s_setprio(0);

        // ---- phase 3: s_j = u_j * cos(30*z1_j) (unpack packed cos) -> HTS ----
        #pragma unroll
        for (int jt = 0; jt < 4; ++jt) {
            #pragma unroll
            for (int q = 0; q < 4; ++q) {
                const uint2 cw = csp[jt][q];
                const float q0 = __uint_as_float(cw.x << 16);
                const float q1 = __uint_as_float(cw.x & 0xffff0000u);
                const float q2 = __uint_as_float(cw.y << 16);
                const float q3 = __uint_as_float(cw.y & 0xffff0000u);
                *(uint2*)(hhB + jt * 2048 + (q >> 1) * 1024 + (q & 1) * 512 + wbB)
                    = pk4hi(c2[jt][q * 4 + 0] * q0, c2[jt][q * 4 + 1] * q1,
                            c2[jt][q * 4 + 2] * q2, c2[jt][q * 4 + 3] * q3);
            }
        }

        // ---- G3: dx[32 k'][32 p] = W1B x s (two chains for latency) ----
        f32x16 c3a = {0.f,0.f,0.f,0.f,0.f,0.f,0.f,0.f,0.f,0.f,0.f,0.f,0.f,0.f,0.f,0.f};
        f32x16 c3b = {0.f,0.f,0.f,0.f,0.f,0.f,0.f,0.f,0.f,0.f,0.f,0.f,0.f,0.f,0.f,0.f};
        __builtin_amdgcn_s_setprio(1);
        #pragma unroll
        for (int ks = 0; ks < 8; ks += 2) {
            const bf16x8 b0 = *(const bf16x8*)(hhB + ks * 1024 + rbB);
            const bf16x8 a0 = *(const bf16x8*)&sW1B_h[ks * 512 + rbS];
            c3a = MFMA32(a0, b0, c3a);
            const bf16x8 b1 = *(const bf16x8*)(hhB + (ks + 1) * 1024 + rbB);
            const bf16x8 a1 = *(const bf16x8*)&sW1B_h[(ks + 1) * 512 + rbS];
            c3b = MFMA32(a1, b1, c3b);
        }
        __builtin_amdgcn_s_setprio(0);
        // rows: k' = (reg&3)+8*(reg>>2)+4*hi. hi=0 regs0-3 -> k'=0..3; k'=4 = (hi=1, reg0)
        const float r0sum = c3a[0] + c3b[0];
        const float de0 = r0sum;
        const float de1 = c3a[1] + c3b[1];
        const float dpx = c3a[2] + c3b[2];
        const float dpy = c3a[3] + c3b[3];
        const float d4v = __shfl(r0sum, pl + 32);   // k'=4 from partner lane

        // ---- epilogue: recompute trilerp geometry from carried px,py,pz ----
        if (lane < 32 && p < N) {
            const float ux = (px + 1.f) * 7.5f;
            const float uy = (py + 1.f) * 7.5f;
            const float uz = (pz + 1.f) * 7.5f;
            int ix = (int)floorf(ux); ix = ix < 0 ? 0 : (ix > RR - 2 ? RR - 2 : ix);
            int iy = (int)floorf(uy); iy = iy < 0 ? 0 : (iy > RR - 2 ? RR - 2 : iy);
            int iz = (int)floorf(uz); iz = iz < 0 ? 0 : (iz > RR - 2 ? RR - 2 : iz);
            const float fx = ux - (float)ix;
            const float fy = uy - (float)iy;
            const float fz = uz - (float)iz;
            const int cbase = (ix * RR + iy) * RR + iz;
            const float wx0 = 1.f - fx, wx1 = fx;
            const float wy0 = 1.f - fy, wy1 = fy;
            const float wz0 = 1.f - fz, wz1 = fz;
            const float2 r000 = g2[cbase];
            const float2 r001 = g2[cbase + 1];
            const float2 r010 = g2[cbase + RR];
            const float2 r011 = g2[cbase + RR + 1];
            const float2 r100 = g2[cbase + RR * RR];
            const float2 r101 = g2[cbase + RR * RR + 1];
            const float2 r110 = g2[cbase + RR * RR + RR];
            const float2 r111 = g2[cbase + RR * RR + RR + 1];
            const float q000 = r000.x * de0 + r000.y * de1;
            const float q001 = r001.x * de0 + r001.y * de1;
            const float q010 = r010.x * de0 + r010.y * de1;
            const float q011 = r011.x * de0 + r011.y * de1;
            const float q100 = r100.x * de0 + r100.y * de1;
            const float q101 = r101.x * de0 + r101.y * de1;
            const float q110 = r110.x * de0 + r110.y * de1;
            const float q111 = r111.x * de0 + r111.y * de1;
            const float gx = 7.5f * (wy0 * wz0 * (q100 - q000) + wy0 * wz1 * (q101 - q001)
                                   + wy1 * wz0 * (q110 - q010) + wy1 * wz1 * (q111 - q011));
            const float gy = 7.5f * (wx0 * wz0 * (q010 - q000) + wx0 * wz1 * (q011 - q001)
                                   + wx1 * wz0 * (q110 - q100) + wx1 * wz1 * (q111 - q101));
            const float gz = 7.5f * (wx0 * wy0 * (q001 - q000) + wx0 * wy1 * (q011 - q010)
                                   + wx1 * wy0 * (q101 - q100) + wx1 * wy1 * (q111 - q110));
            const bool msk = (px >= -1.f) && (px <= 1.f) && (py >= -1.f) && (py <= 1.f)
                          && (pz >= -1.f) && (pz <= 1.f);
            out[N + 3 * p + 0] = dpx + gx;
            out[N + 3 * p + 1] = dpy + gy;
            out[N + 3 * p + 2] = d4v + gz;
            out[4 * N + p] = msk ? 1.f : 0.f;
        }
    }
}

extern "C" void kernel_launch(void* const* d_in, const int* in_sizes, int n_in,
                              void* d_out, int out_size, void* d_ws, size_t ws_size,
                              hipStream_t stream) {
    const float* pos  = (const float*)d_in[0];
    const float* grid = (const float*)d_in[1];
    const float* W1   = (const float*)d_in[2];
    const float* b1   = (const float*)d_in[3];
    const float* W2   = (const float*)d_in[4];
    const float* b2   = (const float*)d_in[5];
    const float* W3   = (const float*)d_in[6];
    const float* b3   = (const float*)d_in[7];
    float* out = (float*)d_out;
    const int N = in_sizes[0] / 3;
    const int blocks = (N + 2047) / 2048;
    hipLaunchKernelGGL(siren_mfma, dim3(blocks), dim3(512), 0, stream,
                       pos, grid, W1, b1, W2, b2, W3, b3, out, N);
}

// Round 18
// 145.944 us; speedup vs baseline: 2.1325x; 1.0080x over previous
//
#include <hip/hip_runtime.h>
#include <hip/hip_bf16.h>
#include <math.h>

#define RR 16

typedef __attribute__((ext_vector_type(8))) short bf16x8;
typedef __attribute__((ext_vector_type(4))) float f32x4;
typedef __attribute__((ext_vector_type(16))) float f32x16;

#define MFMA32(a, b, c) __builtin_amdgcn_mfma_f32_32x32x16_bf16((a), (b), (c), 0, 0, 0)

static __device__ __forceinline__ unsigned short f2bf(float f) {   // staging only
    union { float f; unsigned u; } v; v.f = f;
    unsigned r = v.u + 0x7fffu + ((v.u >> 16) & 1u);
    return (unsigned short)(r >> 16);
}
static __device__ __forceinline__ float bf2f(unsigned short h) {
    union { float f; unsigned u; } v; v.u = ((unsigned)h) << 16; return v.f;
}

static __device__ __forceinline__ void pk4(float a, float b, float c, float d,
                                           uint2* hi, uint2* lo) {
    union { __hip_bfloat162 b; unsigned u; } H01, H23, L01, L23;
    H01.b = __float22bfloat162_rn(float2{a, b});
    H23.b = __float22bfloat162_rn(float2{c, d});
    const float r0 = __uint_as_float(H01.u << 16);
    const float r1 = __uint_as_float(H01.u & 0xffff0000u);
    const float r2 = __uint_as_float(H23.u << 16);
    const float r3 = __uint_as_float(H23.u & 0xffff0000u);
    L01.b = __float22bfloat162_rn(float2{a - r0, b - r1});
    L23.b = __float22bfloat162_rn(float2{c - r2, d - r3});
    hi->x = H01.u; hi->y = H23.u;
    lo->x = L01.u; lo->y = L23.u;
}
static __device__ __forceinline__ uint2 pk4hi(float a, float b, float c, float d) {
    union { __hip_bfloat162 b; unsigned u; } H01, H23;
    H01.b = __float22bfloat162_rn(float2{a, b});
    H23.b = __float22bfloat162_rn(float2{c, d});
    return uint2{H01.u, H23.u};
}

// 32x32x16 structure (R17) + ks unroll-2 in G1/G2: one-iteration lookahead on
// the HTS b128 load (~120cyc LDS latency) without the 32-deep fragment
// prefetch that caused the R10/R11 spills.
__global__ __launch_bounds__(512, 2)
void siren_mfma(const float* __restrict__ pos, const float* __restrict__ grid,
                const float* __restrict__ W1, const float* __restrict__ b1,
                const float* __restrict__ W2, const float* __restrict__ b2,
                const float* __restrict__ W3, const float* __restrict__ b3,
                float* __restrict__ out, int N)
{
    // ---- LDS: 148,480 B ----
    __shared__ short sW2T[32 * 512];   // G1 A: block(it,ks): W2[j=ks*16+hi*8+e][i=it*32+r]
    __shared__ short sW2N[32 * 512];   // G2 A: block(jt,ks): W2[j=jt*32+r][i=ks*16+hi*8+e]
    __shared__ short sW1T_h[4 * 512];  // G0 A: block(jt): 30*W1/30*b1, k=hi*8+e (hi=1 -> 0)
    __shared__ short sW1T_l[4 * 512];
    __shared__ short sW1B_h[8 * 512];  // G3 A: block(ks): rows k'=0..4 = 30*W1, else 0
    __shared__ float sb2[128];
    __shared__ float sW3[128];
    __shared__ short sHTS[8][4096];    // per-wave 8KB: h -> t -> s in B-frag layout
    const int tid = threadIdx.x;

    // ================= weight staging =================
    #pragma unroll
    for (int pass = 0; pass < 4; ++pass) {   // W2T (strided gather, L2-cached)
        const int slot = pass * 512 + tid;
        const int b = slot >> 6, l = slot & 63;
        const int i = (b >> 3) * 32 + (l & 31);
        const int j0 = (b & 7) * 16 + (l >> 5) * 8;
        bf16x8 h8;
        #pragma unroll
        for (int e = 0; e < 8; ++e) h8[e] = (short)f2bf(W2[(j0 + e) * 128 + i]);
        *(bf16x8*)&sW2T[b * 512 + l * 8] = h8;
    }
    #pragma unroll
    for (int pass = 0; pass < 4; ++pass) {   // W2N (contiguous)
        const int slot = pass * 512 + tid;
        const int b = slot >> 6, l = slot & 63;
        const int j = (b >> 3) * 32 + (l & 31);
        const int i0 = (b & 7) * 16 + (l >> 5) * 8;
        const float4 a = *(const float4*)&W2[j * 128 + i0];
        const float4 bb = *(const float4*)&W2[j * 128 + i0 + 4];
        bf16x8 h8;
        h8[0] = (short)f2bf(a.x);  h8[1] = (short)f2bf(a.y);
        h8[2] = (short)f2bf(a.z);  h8[3] = (short)f2bf(a.w);
        h8[4] = (short)f2bf(bb.x); h8[5] = (short)f2bf(bb.y);
        h8[6] = (short)f2bf(bb.z); h8[7] = (short)f2bf(bb.w);
        *(bf16x8*)&sW2N[b * 512 + l * 8] = h8;
    }
    if (tid < 256) {   // W1T hi/lo, pre-scaled by 30; k>=6 and hi=1 zero
        const int jt = tid >> 6, l = tid & 63;
        const int j = jt * 32 + (l & 31);
        const int khi = l >> 5;
        bf16x8 h8, l8;
        #pragma unroll
        for (int e = 0; e < 8; ++e) {
            const int k = khi * 8 + e;
            const float v = (k < 5) ? 30.f * W1[k * 128 + j]
                                    : (k == 5 ? 30.f * b1[j] : 0.f);
            const unsigned short hs = f2bf(v);
            h8[e] = (short)hs;
            l8[e] = (short)f2bf(v - bf2f(hs));
        }
        *(bf16x8*)&sW1T_h[jt * 512 + l * 8] = h8;
        *(bf16x8*)&sW1T_l[jt * 512 + l * 8] = l8;
    }
    {   // W1B hi only, pre-scaled by 30 (all 512 threads)
        const int ks = tid >> 6, l = tid & 63;
        const int kk = l & 31;
        const int j0 = ks * 16 + (l >> 5) * 8;
        bf16x8 h8;
        #pragma unroll
        for (int e = 0; e < 8; ++e) {
            const float v = (kk < 5) ? 30.f * W1[kk * 128 + j0 + e] : 0.f;
            h8[e] = (short)f2bf(v);
        }
        *(bf16x8*)&sW1B_h[ks * 512 + l * 8] = h8;
    }
    if (tid < 128) { sb2[tid] = b2[tid]; sW3[tid] = W3[tid]; }
    const float b3v = b3[0];
    __syncthreads();

    // ================= main loop: 8 tiles of 32 points per wave =================
    const int lane = tid & 63;
    const int wv = tid >> 6;
    const int pl = lane & 31;     // point within tile (C column)
    const int hi = lane >> 5;     // k-group / row-group half
    char* __restrict__ hhB = (char*)sHTS[wv];
    const int rbB = lane * 16;    // byte base for B-frag reads
    const int rbS = lane * 8;     // short base for weight A-frag reads
    const int wbB = pl * 16 + hi * 8;  // byte base for phase writes
    const float2* __restrict__ g2 = (const float2*)grid;

    #pragma unroll 1
    for (int pt = 0; pt < 8; ++pt) {
        const int p = blockIdx.x * 2048 + wv * 256 + pt * 32 + pl;
        const int pc = (p < N) ? p : (N - 1);

        const float px = pos[3 * pc + 0];
        const float py = pos[3 * pc + 1];
        const float pz = pos[3 * pc + 2];

        // ---- trilerp forward (2x redundant across hi) -> x fragment ----
        bf16x8 xbh, xbl;
        {
            const float ux = (px + 1.f) * 7.5f;
            const float uy = (py + 1.f) * 7.5f;
            const float uz = (pz + 1.f) * 7.5f;
            int ix = (int)floorf(ux); ix = ix < 0 ? 0 : (ix > RR - 2 ? RR - 2 : ix);
            int iy = (int)floorf(uy); iy = iy < 0 ? 0 : (iy > RR - 2 ? RR - 2 : iy);
            int iz = (int)floorf(uz); iz = iz < 0 ? 0 : (iz > RR - 2 ? RR - 2 : iz);
            const float fx = ux - (float)ix;
            const float fy = uy - (float)iy;
            const float fz = uz - (float)iz;
            const int cbase = (ix * RR + iy) * RR + iz;
            const float wx0 = 1.f - fx, wx1 = fx;
            const float wy0 = 1.f - fy, wy1 = fy;
            const float wz0 = 1.f - fz, wz1 = fz;
            const float2 c000 = g2[cbase];
            const float2 c001 = g2[cbase + 1];
            const float2 c010 = g2[cbase + RR];
            const float2 c011 = g2[cbase + RR + 1];
            const float2 c100 = g2[cbase + RR * RR];
            const float2 c101 = g2[cbase + RR * RR + 1];
            const float2 c110 = g2[cbase + RR * RR + RR];
            const float2 c111 = g2[cbase + RR * RR + RR + 1];
            const float w000 = wx0 * wy0 * wz0, w001 = wx0 * wy0 * wz1;
            const float w010 = wx0 * wy1 * wz0, w011 = wx0 * wy1 * wz1;
            const float w100 = wx1 * wy0 * wz0, w101 = wx1 * wy0 * wz1;
            const float w110 = wx1 * wy1 * wz0, w111 = wx1 * wy1 * wz1;
            const float e0 = w000 * c000.x + w001 * c001.x + w010 * c010.x
                           + w011 * c011.x + w100 * c100.x + w101 * c101.x
                           + w110 * c110.x + w111 * c111.x;
            const float e1 = w000 * c000.y + w001 * c001.y + w010 * c010.y
                           + w011 * c011.y + w100 * c100.y + w101 * c101.y
                           + w110 * c110.y + w111 * c111.y;
            union { bf16x8 v; uint2 u[2]; } XH, XL;
            pk4(e0, e1, px, py, &XH.u[0], &XL.u[0]);
            pk4(pz, 1.f, 0.f, 0.f, &XH.u[1], &XL.u[1]);
            xbh = XH.v; xbl = XL.v;
        }
        if (lane >= 32) {   // hi half supplies k=8..15 of x (all zero)
            const bf16x8 z8 = {0, 0, 0, 0, 0, 0, 0, 0};
            xbh = z8; xbl = z8;
        }

        // ---- G0 + h-phase fused per jt: c0 tile -> sin to LDS, cos packed regs ----
        uint2 csp[4][4];   // cos(30*z1) as bf16, 32 VGPRs
        #pragma unroll
        for (int jt = 0; jt < 4; ++jt) {
            const bf16x8 ah = *(const bf16x8*)&sW1T_h[jt * 512 + rbS];
            const bf16x8 al = *(const bf16x8*)&sW1T_l[jt * 512 + rbS];
            f32x16 c = {0.f,0.f,0.f,0.f,0.f,0.f,0.f,0.f,0.f,0.f,0.f,0.f,0.f,0.f,0.f,0.f};
            c = MFMA32(ah, xbh, c);
            c = MFMA32(ah, xbl, c);
            c = MFMA32(al, xbh, c);
            #pragma unroll
            for (int q = 0; q < 4; ++q) {
                float s0, s1, s2, s3, q0, q1, q2, q3;
                __sincosf(c[q * 4 + 0], &s0, &q0);
                __sincosf(c[q * 4 + 1], &s1, &q1);
                __sincosf(c[q * 4 + 2], &s2, &q2);
                __sincosf(c[q * 4 + 3], &s3, &q3);
                csp[jt][q] = pk4hi(q0, q1, q2, q3);
                *(uint2*)(hhB + jt * 2048 + (q >> 1) * 1024 + (q & 1) * 512 + wbB)
                    = pk4hi(s0, s1, s2, s3);
            }
        }

        // ---- G1: z2[128 i][32 p] = W2T x h, seeded with b2 ----
        f32x16 c1[4];
        #pragma unroll
        for (int it = 0; it < 4; ++it) {
            #pragma unroll
            for (int q = 0; q < 4; ++q) {
                const f32x4 bv = *(const f32x4*)&sb2[it * 32 + q * 8 + hi * 4];
                c1[it][q * 4 + 0] = bv[0];
                c1[it][q * 4 + 1] = bv[1];
                c1[it][q * 4 + 2] = bv[2];
                c1[it][q * 4 + 3] = bv[3];
            }
        }
        __builtin_amdgcn_s_setprio(1);
        #pragma unroll 2
        for (int ks = 0; ks < 8; ++ks) {
            const bf16x8 bh = *(const bf16x8*)(hhB + ks * 1024 + rbB);
            #pragma unroll
            for (int it = 0; it < 4; ++it) {
                const bf16x8 a = *(const bf16x8*)&sW2T[(it * 8 + ks) * 512 + rbS];
                c1[it] = MFMA32(a, bh, c1[it]);
            }
        }
        __builtin_amdgcn_s_setprio(0);

        // ---- phase 2: sdf partial + t = W3*cos(z2) -> HTS ----
        float sdfp = 0.f;
        #pragma unroll
        for (int it = 0; it < 4; ++it) {
            #pragma unroll
            for (int q = 0; q < 4; ++q) {
                const f32x4 w3v = *(const f32x4*)&sW3[it * 32 + q * 8 + hi * 4];
                float s0, cc0, s1, cc1, s2, cc2, s3, cc3;
                __sincosf(c1[it][q * 4 + 0], &s0, &cc0);
                __sincosf(c1[it][q * 4 + 1], &s1, &cc1);
                __sincosf(c1[it][q * 4 + 2], &s2, &cc2);
                __sincosf(c1[it][q * 4 + 3], &s3, &cc3);
                sdfp = fmaf(w3v[0], s0, sdfp);
                sdfp = fmaf(w3v[1], s1, sdfp);
                sdfp = fmaf(w3v[2], s2, sdfp);
                sdfp = fmaf(w3v[3], s3, sdfp);
                *(uint2*)(hhB + it * 2048 + (q >> 1) * 1024 + (q & 1) * 512 + wbB)
                    = pk4hi(w3v[0] * cc0, w3v[1] * cc1, w3v[2] * cc2, w3v[3] * cc3);
            }
        }
        sdfp += __shfl_xor(sdfp, 32);
        if (lane < 32 && p < N) out[p] = b3v + sdfp;

        // ---- G2: u[128 j][32 p] = W2N x t ----
        f32x16 c2[4];
        #pragma unroll
        for (int jt = 0; jt < 4; ++jt)
            c2[jt] = (f32x16){0.f,0.f,0.f,0.f,0.f,0.f,0.f,0.f,0.f,0.f,0.f,0.f,0.f,0.f,0.f,0.f};
        __builtin_amdgcn_s_setprio(1);
        #pragma unroll 2
        for (int ks = 0; ks < 8; ++ks) {
            const bf16x8 bh = *(const bf16x8*)(hhB + ks * 1024 + rbB);
            #pragma unroll
            for (int jt = 0; jt < 4; ++jt) {
                const bf16x8 a = *(const bf16x8*)&sW2N[(jt * 8 + ks) * 512 + rbS];
                c2[jt] = MFMA32(a, bh, c2[jt]);
            }
        }
        __builtin_amdgcn_s_setprio(0);

        // ---- phase 3: s_j = u_j * cos(30*z1_j) (unpack packed cos) -> HTS ----
        #pragma unroll
        for (int jt = 0; jt < 4; ++jt) {
            #pragma unroll
            for (int q = 0; q < 4; ++q) {
                const uint2 cw = csp[jt][q];
                const float q0 = __uint_as_float(cw.x << 16);
                const float q1 = __uint_as_float(cw.x & 0xffff0000u);
                const float q2 = __uint_as_float(cw.y << 16);
                const float q3 = __uint_as_float(cw.y & 0xffff0000u);
                *(uint2*)(hhB + jt * 2048 + (q >> 1) * 1024 + (q & 1) * 512 + wbB)
                    = pk4hi(c2[jt][q * 4 + 0] * q0, c2[jt][q * 4 + 1] * q1,
                            c2[jt][q * 4 + 2] * q2, c2[jt][q * 4 + 3] * q3);
            }
        }

        // ---- G3: dx[32 k'][32 p] = W1B x s (two chains for latency) ----
        f32x16 c3a = {0.f,0.f,0.f,0.f,0.f,0.f,0.f,0.f,0.f,0.f,0.f,0.f,0.f,0.f,0.f,0.f};
        f32x16 c3b = {0.f,0.f,0.f,0.f,0.f,0.f,0.f,0.f,0.f,0.f,0.f,0.f,0.f,0.f,0.f,0.f};
        __builtin_amdgcn_s_setprio(1);
        #pragma unroll
        for (int ks = 0; ks < 8; ks += 2) {
            const bf16x8 b0 = *(const bf16x8*)(hhB + ks * 1024 + rbB);
            const bf16x8 a0 = *(const bf16x8*)&sW1B_h[ks * 512 + rbS];
            c3a = MFMA32(a0, b0, c3a);
            const bf16x8 b1 = *(const bf16x8*)(hhB + (ks + 1) * 1024 + rbB);
            const bf16x8 a1 = *(const bf16x8*)&sW1B_h[(ks + 1) * 512 + rbS];
            c3b = MFMA32(a1, b1, c3b);
        }
        __builtin_amdgcn_s_setprio(0);
        // rows: k' = (reg&3)+8*(reg>>2)+4*hi. hi=0 regs0-3 -> k'=0..3; k'=4 = (hi=1, reg0)
        const float r0sum = c3a[0] + c3b[0];
        const float de0 = r0sum;
        const float de1 = c3a[1] + c3b[1];
        const float dpx = c3a[2] + c3b[2];
        const float dpy = c3a[3] + c3b[3];
        const float d4v = __shfl(r0sum, pl + 32);   // k'=4 from partner lane

        // ---- epilogue: recompute trilerp geometry from carried px,py,pz ----
        if (lane < 32 && p < N) {
            const float ux = (px + 1.f) * 7.5f;
            const float uy = (py + 1.f) * 7.5f;
            const float uz = (pz + 1.f) * 7.5f;
            int ix = (int)floorf(ux); ix = ix < 0 ? 0 : (ix > RR - 2 ? RR - 2 : ix);
            int iy = (int)floorf(uy); iy = iy < 0 ? 0 : (iy > RR - 2 ? RR - 2 : iy);
            int iz = (int)floorf(uz); iz = iz < 0 ? 0 : (iz > RR - 2 ? RR - 2 : iz);
            const float fx = ux - (float)ix;
            const float fy = uy - (float)iy;
            const float fz = uz - (float)iz;
            const int cbase = (ix * RR + iy) * RR + iz;
            const float wx0 = 1.f - fx, wx1 = fx;
            const float wy0 = 1.f - fy, wy1 = fy;
            const float wz0 = 1.f - fz, wz1 = fz;
            const float2 r000 = g2[cbase];
            const float2 r001 = g2[cbase + 1];
            const float2 r010 = g2[cbase + RR];
            const float2 r011 = g2[cbase + RR + 1];
            const float2 r100 = g2[cbase + RR * RR];
            const float2 r101 = g2[cbase + RR * RR + 1];
            const float2 r110 = g2[cbase + RR * RR + RR];
            const float2 r111 = g2[cbase + RR * RR + RR + 1];
            const float q000 = r000.x * de0 + r000.y * de1;
            const float q001 = r001.x * de0 + r001.y * de1;
            const float q010 = r010.x * de0 + r010.y * de1;
            const float q011 = r011.x * de0 + r011.y * de1;
            const float q100 = r100.x * de0 + r100.y * de1;
            const float q101 = r101.x * de0 + r101.y * de1;
            const float q110 = r110.x * de0 + r110.y * de1;
            const float q111 = r111.x * de0 + r111.y * de1;
            const float gx = 7.5f * (wy0 * wz0 * (q100 - q000) + wy0 * wz1 * (q101 - q001)
                                   + wy1 * wz0 * (q110 - q010) + wy1 * wz1 * (q111 - q011));
            const float gy = 7.5f * (wx0 * wz0 * (q010 - q000) + wx0 * wz1 * (q011 - q001)
                                   + wx1 * wz0 * (q110 - q100) + wx1 * wz1 * (q111 - q101));
            const float gz = 7.5f * (wx0 * wy0 * (q001 - q000) + wx0 * wy1 * (q011 - q010)
                                   + wx1 * wy0 * (q101 - q100) + wx1 * wy1 * (q111 - q110));
            const bool msk = (px >= -1.f) && (px <= 1.f) && (py >= -1.f) && (py <= 1.f)
                          && (pz >= -1.f) && (pz <= 1.f);
            out[N + 3 * p + 0] = dpx + gx;
            out[N + 3 * p + 1] = dpy + gy;
            out[N + 3 * p + 2] = d4v + gz;
            out[4 * N + p] = msk ? 1.f : 0.f;
        }
    }
}

extern "C" void kernel_launch(void* const* d_in, const int* in_sizes, int n_in,
                              void* d_out, int out_size, void* d_ws, size_t ws_size,
                              hipStream_t stream) {
    const float* pos  = (const float*)d_in[0];
    const float* grid = (const float*)d_in[1];
    const float* W1   = (const float*)d_in[2];
    const float* b1   = (const float*)d_in[3];
    const float* W2   = (const float*)d_in[4];
    const float* b2   = (const float*)d_in[5];
    const float* W3   = (const float*)d_in[6];
    const float* b3   = (const float*)d_in[7];
    float* out = (float*)d_out;
    const int N = in_sizes[0] / 3;
    const int blocks = (N + 2047) / 2048;
    hipLaunchKernelGGL(siren_mfma, dim3(blocks), dim3(512), 0, stream,
                       pos, grid, W1, b1, W2, b2, W3, b3, out, N);
}